// Round 10
// baseline (63.045 us; speedup 1.0000x reference)
//
#include <hip/hip_runtime.h>

// HBV hydrological model, MI355X (gfx950).
// x (365,1000,3) f32, parameters (365,1000,14,16) f32, staind i32 -> out (365,1000,1) f32.
//
// Latency-bound serial scan (250 waves, 1 wave/CU -- occupancy is structurally 1,
// 99KB LDS already caps blocks/CU at 1). R10 key change: amdgpu_waves_per_eu(1,1)
// -- declare the TRUE occupancy target so the GCN scheduler stops scheduling for
// register thrift (VGPR=32 since R1 = minimal live ranges = serialized dependent
// chains) and interleaves ring refills + off-chain prep + pow chains across stalls.
// (R9 set only the MIN waves/EU -- a no-op; this sets the MAX.)
// Carried from R8: single-log pow algebra, deferred mu-reduction, depth-10 register
// ring, LDS-staged output, coalesced flush.

static constexpr int   NSTEP = 365;
static constexpr int   NGRID = 1000;
static constexpr int   MU    = 16;
static constexpr float PRECS = 1e-5f;
static constexpr int   DEPTH = 10;
static constexpr int   QPAD  = 68;     // qlds row stride (words): 64 + 4 pad

__global__ __launch_bounds__(64)
__attribute__((amdgpu_waves_per_eu(1, 1)))
void hbv_kernel(const float* __restrict__ x,
                const float* __restrict__ par,
                const int*   __restrict__ staind_p,
                float*       __restrict__ out)
{
    __shared__ float qlds[NSTEP * QPAD];   // 99,280 B: per-lane Q per step

    const int lane = threadIdx.x;          // 0..63
    const int m    = lane & 15;            // mu index
    const int gl   = lane >> 4;            // 0..3 local g
    const int gbase = blockIdx.x * 4;
    const int g    = gbase + gl;
    const int staind = *staind_p;

    const size_t tstride = (size_t)NGRID * 14 * MU;
    const int    xstride = NGRID * 3;

    // ---- static params: parameters[staind, g, i, m] ----
    const float* ps = par + (size_t)staind * tstride + (size_t)g * 14 * MU + m;
    const float FC    = 50.0f  + ps[ 1*MU] * (1000.0f - 50.0f);
    const float K0    = 0.05f  + ps[ 2*MU] * (0.9f  - 0.05f);
    const float K1    = 0.01f  + ps[ 3*MU] * (0.5f  - 0.01f);
    const float K2    = 0.001f + ps[ 4*MU] * (0.2f  - 0.001f);
    const float LP    = 0.2f   + ps[ 5*MU] * (1.0f  - 0.2f);
    const float PERCp =          ps[ 6*MU] * 10.0f;
    const float UZL   =          ps[ 7*MU] * 100.0f;
    const float TT    = -2.5f  + ps[ 8*MU] * 5.0f;
    const float CFMAX = 0.5f   + ps[ 9*MU] * (10.0f - 0.5f);
    const float CRF   =          ps[10*MU] * 0.1f * CFMAX;
    const float CWH   =          ps[11*MU] * 0.2f;
    const float C     =          ps[13*MU] * 1.0f;
    const float rFC   = 1.0f / FC;
    // log-domain constants (same v_log instruction as in-loop -> exact identity
    // log2(min(SM,FC)) == min(log2(SM), lgFC))
    const float lgFC   = __builtin_amdgcn_logf(FC);
    const float lgLPFC = __builtin_amdgcn_logf(LP * FC);

    // ---- state ----
    float SP = 1e-3f, MW = 1e-3f, SM = 1e-3f, SUZ = 1e-3f, SLZ = 1e-3f;

    auto step = [&](int t, float P, float T, float E, float p0, float p12) {
        // off-chain prep (depends only on ring inputs)
        const float BETA    = 1.0f + p0  * 5.0f;
        const float BETAET  = 0.3f + p12 * 4.7f;
        const float nBlgFC  = -BETA   * lgFC;
        const float nBElgLP = -BETAET * lgLPFC;
        const float RAIN = (T >= TT) ? P : 0.0f;
        const float SNOW = P - RAIN;                       // exact split
        const float dT   = T - TT;
        const float acap = fmaxf(CFMAX * dT, 0.0f);
        const float bcap = fmaxf(CRF * (-dT), 0.0f);

        // snow module (SP, MW)
        const float SP1  = SP + SNOW;
        const float melt = fminf(acap, SP1);
        const float SP2  = SP1 - melt;
        const float MW1  = MW + melt;
        const float refr = fminf(bcap, MW1);
        const float MW2  = MW1 - refr;
        const float SP3  = SP2 + refr;
        const float lim  = CWH * SP3;
        const float tosoil = fmaxf(MW2 - lim, 0.0f);
        SP = SP3;
        MW = fminf(MW2, lim);                              // MW2 - tosoil (exact)

        // soil module -- single-log form
        const float lg    = __builtin_amdgcn_logf(SM);     // log2(SM), SM >= PRECS
        const float wet   = __builtin_amdgcn_exp2f(fminf(fmaf(BETA, lg, nBlgFC), 0.0f));
        const float excess = fmaxf(SM - FC, 0.0f);
        const float SM1   = fminf(SM, FC);                 // SM - excess (exact)
        const float lg1   = fminf(lg, lgFC);               // log2(SM1) (exact)
        const float evapf = __builtin_amdgcn_exp2f(fminf(fmaf(BETAET, lg1, nBElgLP), 0.0f));
        const float SM2   = fmaxf(fmaf(-E, evapf, SM1), PRECS);   // ETact fold (exact)
        const float rt    = RAIN + tosoil;
        const float recharge = rt * wet;
        const float SM3   = SM2 + rt - recharge;
        const float capf  = fmaxf(fmaf(-SM3, rFC, 1.0f), 0.0f);   // 1-min(s,1)=max(1-s,0)
        const float cap   = fminf(SLZ, (C * SLZ) * capf);
        SM = fmaxf(SM3 + cap, PRECS);
        const float SLZ1  = fmaxf(SLZ - cap, PRECS);

        // response
        const float SUZ1 = SUZ + recharge + excess;
        const float PERC = fminf(SUZ1, PERCp);
        const float SUZ2 = SUZ1 - PERC;
        const float Q0   = K0 * fmaxf(SUZ2 - UZL, 0.0f);
        const float SUZ3 = SUZ2 - Q0;
        const float Q1   = K1 * SUZ3;
        SUZ = SUZ3 - Q1;
        const float SLZ2 = SLZ1 + PERC;
        const float Q2   = K2 * SLZ2;
        SLZ = SLZ2 - Q2;

        // per-lane Q to LDS; mu-reduction deferred to the flush
        qlds[t * QPAD + lane] = Q0 + Q1 + Q2;
    };

    // ---- depth-10 register ring ----
    const float* pd = par + (size_t)g * 14 * MU + m;
    const float* xp = x   + (size_t)g * 3;

    float bP[DEPTH], bT[DEPTH], bE[DEPTH], b0[DEPTH], b12[DEPTH];
    const float* pdp = pd;
    const float* xpp = xp;
#pragma unroll
    for (int j = 0; j < DEPTH; ++j) {      // slots 0..9 = steps 0..9
        b0[j]  = pdp[0];
        b12[j] = pdp[12*MU];
        const float3 v = *(const float3*)xpp;
        bP[j] = v.x; bT[j] = v.y; bE[j] = v.z;
        pdp += tstride;
        xpp += xstride;
    }

    // main: steps 0..349, refills steps 10..359 -- unconditional advance
    for (int tb = 0; tb < 350; tb += DEPTH) {
#pragma unroll
        for (int j = 0; j < DEPTH; ++j) {
            const float P = bP[j], T = bT[j], E = bE[j], p0 = b0[j], p12 = b12[j];
            b0[j]  = pdp[0];
            b12[j] = pdp[12*MU];
            const float3 v = *(const float3*)xpp;
            bP[j] = v.x; bT[j] = v.y; bE[j] = v.z;
            pdp += tstride;
            xpp += xstride;
            step(tb + j, P, T, E, p0, p12);
        }
    }

    // peeled block: steps 350..359, refill rows 360..364 then stop advancing
#pragma unroll
    for (int j = 0; j < DEPTH; ++j) {
        const float P = bP[j], T = bT[j], E = bE[j], p0 = b0[j], p12 = b12[j];
        b0[j]  = pdp[0];
        b12[j] = pdp[12*MU];
        const float3 v = *(const float3*)xpp;
        bP[j] = v.x; bT[j] = v.y; bE[j] = v.z;
        if (j < 4) { pdp += tstride; xpp += xstride; }   // stop at row 364
        step(350 + j, P, T, E, p0, p12);
    }

    // epilogue: steps 360..364 from slots 0..4
#pragma unroll
    for (int j = 0; j < 5; ++j)
        step(360 + j, bP[j], bT[j], bE[j], b0[j], b12[j]);

    // ---- flush: 16-lane sums + coalesced global stores (1 wave/block, no barrier;
    //      compiler inserts the lgkmcnt wait before the LDS reads) ----
    for (int i = lane; i < NSTEP * 4; i += 64) {
        const int t  = i >> 2;
        const int gg = i & 3;
        const float* row = &qlds[t * QPAD + gg * 16];
        float s = 0.0f;
#pragma unroll
        for (int k = 0; k < 16; ++k) s += row[k];
        out[t * NGRID + gbase + gg] = s * 0.0625f;
    }
}

extern "C" void kernel_launch(void* const* d_in, const int* in_sizes, int n_in,
                              void* d_out, int out_size, void* d_ws, size_t ws_size,
                              hipStream_t stream) {
    const float* x      = (const float*)d_in[0];
    const float* par    = (const float*)d_in[1];
    const int*   staind = (const int*)d_in[2];
    float*       out    = (float*)d_out;

    hipLaunchKernelGGL(hbv_kernel, dim3(NGRID / 4), dim3(64), 0, stream,
                       x, par, staind, out);
}

// Round 11
// 61.086 us; speedup vs baseline: 1.0321x; 1.0321x over previous
//
#include <hip/hip_runtime.h>

// HBV hydrological model, MI355X (gfx950).
// x (365,1000,3) f32, parameters (365,1000,14,16) f32, staind i32 -> out (365,1000,1) f32.
//
// Latency-bound serial scan (250 waves, 1 wave/CU). R11: per-step time = ~140cy issue
// + ~270cy fixed stall (R8: -9 ops -> exactly -18cy). Hypothesis: the fixed stall is
// in-order vmcnt waits on ring refills interleaved into the step stream (newest loads
// only ~400cy old at consumption; also explains R6's null -- waits sat between the
// pipeline stages). Fix: double-buffered REGISTER BANKS -- all 30 loads for block k+1
// issued back-to-back at block k start; the 10-step stretch is pure ALU (Q buffered,
// ds_writes batched at block end). Consumed loads are ~3000cy old -> vmcnt always
// satisfied.
// Carried from R8: single-log pow algebra, deferred mu-reduction, LDS-staged output.

static constexpr int   NSTEP = 365;
static constexpr int   NGRID = 1000;
static constexpr int   MU    = 16;
static constexpr float PRECS = 1e-5f;
static constexpr int   QPAD  = 68;     // qlds row stride (words): 64 + 4 pad

__global__ __launch_bounds__(64)
__attribute__((amdgpu_waves_per_eu(1, 1)))
void hbv_kernel(const float* __restrict__ x,
                const float* __restrict__ par,
                const int*   __restrict__ staind_p,
                float*       __restrict__ out)
{
    __shared__ float qlds[NSTEP * QPAD];   // 99,280 B: per-lane Q per step

    const int lane = threadIdx.x;          // 0..63
    const int m    = lane & 15;            // mu index
    const int gl   = lane >> 4;            // 0..3 local g
    const int gbase = blockIdx.x * 4;
    const int g    = gbase + gl;
    const int staind = *staind_p;

    const size_t tstride = (size_t)NGRID * 14 * MU;
    const int    xstride = NGRID * 3;
    const int    lp = g * (14 * MU) + m;   // per-lane param offset within a step row
    const int    lx = g * 3;               // per-lane x offset within a step row

    // ---- static params: parameters[staind, g, i, m] ----
    const float* ps = par + (size_t)staind * tstride + lp;
    const float FC    = 50.0f  + ps[ 1*MU] * (1000.0f - 50.0f);
    const float K0    = 0.05f  + ps[ 2*MU] * (0.9f  - 0.05f);
    const float K1    = 0.01f  + ps[ 3*MU] * (0.5f  - 0.01f);
    const float K2    = 0.001f + ps[ 4*MU] * (0.2f  - 0.001f);
    const float LP    = 0.2f   + ps[ 5*MU] * (1.0f  - 0.2f);
    const float PERCp =          ps[ 6*MU] * 10.0f;
    const float UZL   =          ps[ 7*MU] * 100.0f;
    const float TT    = -2.5f  + ps[ 8*MU] * 5.0f;
    const float CFMAX = 0.5f   + ps[ 9*MU] * (10.0f - 0.5f);
    const float CRF   =          ps[10*MU] * 0.1f * CFMAX;
    const float CWH   =          ps[11*MU] * 0.2f;
    const float C     =          ps[13*MU] * 1.0f;
    const float rFC   = 1.0f / FC;
    const float lgFC   = __builtin_amdgcn_logf(FC);
    const float lgLPFC = __builtin_amdgcn_logf(LP * FC);

    // ---- state ----
    float SP = 1e-3f, MW = 1e-3f, SM = 1e-3f, SUZ = 1e-3f, SLZ = 1e-3f;

    auto step = [&](float P, float T, float E, float p0, float p12) -> float {
        // off-chain prep
        const float BETA    = 1.0f + p0  * 5.0f;
        const float BETAET  = 0.3f + p12 * 4.7f;
        const float nBlgFC  = -BETA   * lgFC;
        const float nBElgLP = -BETAET * lgLPFC;
        const float RAIN = (T >= TT) ? P : 0.0f;
        const float SNOW = P - RAIN;                       // exact split
        const float dT   = T - TT;
        const float acap = fmaxf(CFMAX * dT, 0.0f);
        const float bcap = fmaxf(CRF * (-dT), 0.0f);

        // snow module (SP, MW)
        const float SP1  = SP + SNOW;
        const float melt = fminf(acap, SP1);
        const float SP2  = SP1 - melt;
        const float MW1  = MW + melt;
        const float refr = fminf(bcap, MW1);
        const float MW2  = MW1 - refr;
        const float SP3  = SP2 + refr;
        const float lim  = CWH * SP3;
        const float tosoil = fmaxf(MW2 - lim, 0.0f);
        SP = SP3;
        MW = fminf(MW2, lim);                              // MW2 - tosoil (exact)

        // soil module -- single-log form
        const float lg    = __builtin_amdgcn_logf(SM);     // log2(SM), SM >= PRECS
        const float wet   = __builtin_amdgcn_exp2f(fminf(fmaf(BETA, lg, nBlgFC), 0.0f));
        const float excess = fmaxf(SM - FC, 0.0f);
        const float SM1   = fminf(SM, FC);                 // SM - excess (exact)
        const float lg1   = fminf(lg, lgFC);               // log2(SM1) (exact)
        const float evapf = __builtin_amdgcn_exp2f(fminf(fmaf(BETAET, lg1, nBElgLP), 0.0f));
        const float SM2   = fmaxf(fmaf(-E, evapf, SM1), PRECS);
        const float rt    = RAIN + tosoil;
        const float recharge = rt * wet;
        const float SM3   = SM2 + rt - recharge;
        const float capf  = fmaxf(fmaf(-SM3, rFC, 1.0f), 0.0f);
        const float cap   = fminf(SLZ, (C * SLZ) * capf);
        SM = fmaxf(SM3 + cap, PRECS);
        const float SLZ1  = fmaxf(SLZ - cap, PRECS);

        // response
        const float SUZ1 = SUZ + recharge + excess;
        const float PERC = fminf(SUZ1, PERCp);
        const float SUZ2 = SUZ1 - PERC;
        const float Q0   = K0 * fmaxf(SUZ2 - UZL, 0.0f);
        const float SUZ3 = SUZ2 - Q0;
        const float Q1   = K1 * SUZ3;
        SUZ = SUZ3 - Q1;
        const float SLZ2 = SLZ1 + PERC;
        const float Q2   = K2 * SLZ2;
        SLZ = SLZ2 - Q2;

        return Q0 + Q1 + Q2;
    };

    // ---- double-buffered register banks (all statically indexed via macros) ----
    float aP[10], aT[10], aE[10], a0[10], a12[10];
    float cP[10], cT[10], cE[10], c0[10], c12[10];
    const float* prow = par;   // uniform step-row base, advances tstride per row
    const float* xrow = x;     // uniform step-row base, advances xstride per row

#define LOADB(BP, BT, BE, B0, B12, N)                            \
    _Pragma("unroll") for (int j = 0; j < (N); ++j) {            \
        B0[j]  = prow[lp];                                       \
        B12[j] = prow[lp + 192];                                 \
        const float3 v = *(const float3*)(xrow + lx);            \
        BP[j] = v.x; BT[j] = v.y; BE[j] = v.z;                   \
        prow += tstride; xrow += xstride;                        \
    }

#define COMPB(BP, BT, BE, B0, B12, T0, N)                        \
    {                                                            \
        float qreg[10];                                          \
        _Pragma("unroll") for (int j = 0; j < (N); ++j)          \
            qreg[j] = step(BP[j], BT[j], BE[j], B0[j], B12[j]);  \
        _Pragma("unroll") for (int j = 0; j < (N); ++j)          \
            qlds[((T0) + j) * QPAD + lane] = qreg[j];            \
    }

    LOADB(aP, aT, aE, a0, a12, 10)             // rows 0..9

    for (int bb = 0; bb < 17; ++bb) {          // 17 double-blocks = steps 0..339
        const int t0 = bb * 20;
        LOADB(cP, cT, cE, c0, c12, 10)         // rows t0+10 .. t0+19
        COMPB(aP, aT, aE, a0, a12, t0, 10)     // steps t0 .. t0+9 (pure ALU)
        LOADB(aP, aT, aE, a0, a12, 10)         // rows t0+20 .. t0+29
        COMPB(cP, cT, cE, c0, c12, t0 + 10, 10)
    }
    // invariant: bank a holds rows 340..349, prow at row 350

    LOADB(cP, cT, cE, c0, c12, 10)             // rows 350..359
    COMPB(aP, aT, aE, a0, a12, 340, 10)        // steps 340..349
    LOADB(aP, aT, aE, a0, a12, 5)              // rows 360..364
    COMPB(cP, cT, cE, c0, c12, 350, 10)        // steps 350..359
    COMPB(aP, aT, aE, a0, a12, 360, 5)         // steps 360..364

#undef LOADB
#undef COMPB

    // ---- flush: 16-lane sums + coalesced global stores (1 wave/block, no barrier;
    //      compiler inserts the lgkmcnt wait before the LDS reads) ----
    for (int i = lane; i < NSTEP * 4; i += 64) {
        const int t  = i >> 2;
        const int gg = i & 3;
        const float* row = &qlds[t * QPAD + gg * 16];
        float s = 0.0f;
#pragma unroll
        for (int k = 0; k < 16; ++k) s += row[k];
        out[t * NGRID + gbase + gg] = s * 0.0625f;
    }
}

extern "C" void kernel_launch(void* const* d_in, const int* in_sizes, int n_in,
                              void* d_out, int out_size, void* d_ws, size_t ws_size,
                              hipStream_t stream) {
    const float* x      = (const float*)d_in[0];
    const float* par    = (const float*)d_in[1];
    const int*   staind = (const int*)d_in[2];
    float*       out    = (float*)d_out;

    hipLaunchKernelGGL(hbv_kernel, dim3(NGRID / 4), dim3(64), 0, stream,
                       x, par, staind, out);
}

// Round 12
// 58.217 us; speedup vs baseline: 1.0829x; 1.0493x over previous
//
#include <hip/hip_runtime.h>

// HBV hydrological model, MI355X (gfx950).
// x (365,1000,3) f32, parameters (365,1000,14,16) f32, staind i32 -> out (365,1000,1) f32.
//
// Latency-bound serial scan (250 waves, 1 wave/CU). Surviving model after R4-R11:
// per-step time ~400cy = the step's dependent spine executed nearly in order at
// ~5-8cy per dependent op (single wave, no TLP). R12: dependent-path surgery --
// med3 for clamp sites (scale-mul off-path), parallel RAIN/SNOW cndmask pair,
// shared log-domain clamp for both pows, decay-mul state updates (independent of
// Q-muls), early SUZ+excess. All rewrites exact or ulp-level (20x threshold headroom).
// Carried: R11 batched register banks (20-step double-buffer), deferred mu-reduce,
// LDS-staged output, coalesced flush.

static constexpr int   NSTEP = 365;
static constexpr int   NGRID = 1000;
static constexpr int   MU    = 16;
static constexpr float PRECS = 1e-5f;
static constexpr int   QPAD  = 68;     // qlds row stride (words): 64 + 4 pad

__global__ __launch_bounds__(64)
__attribute__((amdgpu_waves_per_eu(1, 1)))
void hbv_kernel(const float* __restrict__ x,
                const float* __restrict__ par,
                const int*   __restrict__ staind_p,
                float*       __restrict__ out)
{
    __shared__ float qlds[NSTEP * QPAD];   // 99,280 B: per-lane Q per step

    const int lane = threadIdx.x;          // 0..63
    const int m    = lane & 15;            // mu index
    const int gl   = lane >> 4;            // 0..3 local g
    const int gbase = blockIdx.x * 4;
    const int g    = gbase + gl;
    const int staind = *staind_p;

    const size_t tstride = (size_t)NGRID * 14 * MU;
    const int    xstride = NGRID * 3;
    const int    lp = g * (14 * MU) + m;   // per-lane param offset within a step row
    const int    lx = g * 3;               // per-lane x offset within a step row

    // ---- static params: parameters[staind, g, i, m] ----
    const float* ps = par + (size_t)staind * tstride + lp;
    const float FC    = 50.0f  + ps[ 1*MU] * (1000.0f - 50.0f);
    const float K0    = 0.05f  + ps[ 2*MU] * (0.9f  - 0.05f);
    const float K1    = 0.01f  + ps[ 3*MU] * (0.5f  - 0.01f);
    const float K2    = 0.001f + ps[ 4*MU] * (0.2f  - 0.001f);
    const float LP    = 0.2f   + ps[ 5*MU] * (1.0f  - 0.2f);
    const float PERCp =          ps[ 6*MU] * 10.0f;
    const float UZL   =          ps[ 7*MU] * 100.0f;
    const float TT    = -2.5f  + ps[ 8*MU] * 5.0f;
    const float CFMAX = 0.5f   + ps[ 9*MU] * (10.0f - 0.5f);
    const float CRF   =          ps[10*MU] * 0.1f * CFMAX;
    const float CWH   =          ps[11*MU] * 0.2f;
    const float C     =          ps[13*MU] * 1.0f;
    const float rFC   = 1.0f / FC;
    const float lgFC   = __builtin_amdgcn_logf(FC);
    const float dlg    = lgFC - __builtin_amdgcn_logf(LP * FC);  // lgFC - lgLPFC
    const float K1c    = 1.0f - K1;
    const float K2c    = 1.0f - K2;

    // ---- state ----
    float SP = 1e-3f, MW = 1e-3f, SM = 1e-3f, SUZ = 1e-3f, SLZ = 1e-3f;

    auto step = [&](float P, float T, float E, float p0, float p12) -> float {
        // off-chain prep
        const float BETA    = 1.0f + p0  * 5.0f;
        const float BETAET  = 0.3f + p12 * 4.7f;
        const float dT      = T - TT;
        const float acap    = CFMAX * dT;        // raw; med3 clamps
        const float bcap    = CRF * (-dT);       // raw; med3 clamps
        const float rain_c  = (T >= TT);
        const float RAIN    = rain_c ? P : 0.0f; // both selects off one compare,
        const float SNOW    = rain_c ? 0.0f : P; // parallel (no dependent sub)

        // snow module (SP, MW)
        const float SP1  = SP + SNOW;
        const float melt = __builtin_amdgcn_fmed3f(acap, 0.0f, SP1);  // SP1 >= 0
        const float SP2  = SP1 - melt;
        const float MW1  = MW + melt;
        const float refr = __builtin_amdgcn_fmed3f(bcap, 0.0f, MW1);  // MW1 >= 0
        const float MW2  = MW1 - refr;
        const float SP3  = SP2 + refr;
        const float lim  = CWH * SP3;
        const float tosoil = fmaxf(MW2 - lim, 0.0f);
        SP = SP3;
        MW = fminf(MW2, lim);                    // MW2 - tosoil (exact)

        // soil module -- shared log-domain clamp for both pows
        const float excess = fmaxf(SM - FC, 0.0f);     // early (needs only SM)
        const float SUZe   = SUZ + excess;             // off-path pre-sum
        const float SM1    = fminf(SM, FC);            // SM - excess (exact)
        const float lg     = __builtin_amdgcn_logf(SM);        // log2(SM), SM >= PRECS
        const float uc     = fminf(lg - lgFC, 0.0f);           // min(log2(SM/FC), 0)
        const float wet    = __builtin_amdgcn_exp2f(BETA * uc);
        const float evapf  = __builtin_amdgcn_exp2f(BETAET * fminf(uc + dlg, 0.0f));
        const float SM2    = fmaxf(fmaf(-E, evapf, SM1), PRECS);  // ETact fold (exact)
        const float rt     = RAIN + tosoil;
        const float recharge = rt * wet;
        const float SM3    = (SM2 + rt) - recharge;
        const float capf   = fmaxf(fmaf(-SM3, rFC, 1.0f), 0.0f);
        const float cap    = fminf(SLZ, (C * SLZ) * capf);
        SM = fmaxf(SM3 + cap, PRECS);
        const float SLZ1   = fmaxf(SLZ - cap, PRECS);

        // response
        const float SUZ1 = SUZe + recharge;
        const float PERC = fminf(SUZ1, PERCp);
        const float SUZ2 = SUZ1 - PERC;
        const float Q0   = K0 * fmaxf(SUZ2 - UZL, 0.0f);
        const float SUZ3 = SUZ2 - Q0;
        const float Q1   = K1 * SUZ3;     // independent pair:
        SUZ = K1c * SUZ3;                 // SUZ3 - Q1 (ulp-level)
        const float SLZ2 = SLZ1 + PERC;
        const float Q2   = K2 * SLZ2;     // independent pair:
        SLZ = K2c * SLZ2;                 // SLZ2 - Q2 (ulp-level)

        return Q0 + Q1 + Q2;
    };

    // ---- double-buffered register banks (all statically indexed via macros) ----
    float aP[10], aT[10], aE[10], a0[10], a12[10];
    float cP[10], cT[10], cE[10], c0[10], c12[10];
    const float* prow = par;   // uniform step-row base, advances tstride per row
    const float* xrow = x;     // uniform step-row base, advances xstride per row

#define LOADB(BP, BT, BE, B0, B12, N)                            \
    _Pragma("unroll") for (int j = 0; j < (N); ++j) {            \
        B0[j]  = prow[lp];                                       \
        B12[j] = prow[lp + 192];                                 \
        const float3 v = *(const float3*)(xrow + lx);            \
        BP[j] = v.x; BT[j] = v.y; BE[j] = v.z;                   \
        prow += tstride; xrow += xstride;                        \
    }

#define COMPB(BP, BT, BE, B0, B12, T0, N)                        \
    {                                                            \
        float qreg[10];                                          \
        _Pragma("unroll") for (int j = 0; j < (N); ++j)          \
            qreg[j] = step(BP[j], BT[j], BE[j], B0[j], B12[j]);  \
        _Pragma("unroll") for (int j = 0; j < (N); ++j)          \
            qlds[((T0) + j) * QPAD + lane] = qreg[j];            \
    }

    LOADB(aP, aT, aE, a0, a12, 10)             // rows 0..9

    for (int bb = 0; bb < 17; ++bb) {          // 17 double-blocks = steps 0..339
        const int t0 = bb * 20;
        LOADB(cP, cT, cE, c0, c12, 10)         // rows t0+10 .. t0+19
        COMPB(aP, aT, aE, a0, a12, t0, 10)     // steps t0 .. t0+9 (pure ALU)
        LOADB(aP, aT, aE, a0, a12, 10)         // rows t0+20 .. t0+29
        COMPB(cP, cT, cE, c0, c12, t0 + 10, 10)
    }
    // invariant: bank a holds rows 340..349, prow at row 350

    LOADB(cP, cT, cE, c0, c12, 10)             // rows 350..359
    COMPB(aP, aT, aE, a0, a12, 340, 10)        // steps 340..349
    LOADB(aP, aT, aE, a0, a12, 5)              // rows 360..364
    COMPB(cP, cT, cE, c0, c12, 350, 10)        // steps 350..359
    COMPB(aP, aT, aE, a0, a12, 360, 5)         // steps 360..364

#undef LOADB
#undef COMPB

    // ---- flush: 16-lane sums + coalesced global stores (1 wave/block, no barrier;
    //      compiler inserts the lgkmcnt wait before the LDS reads) ----
    for (int i = lane; i < NSTEP * 4; i += 64) {
        const int t  = i >> 2;
        const int gg = i & 3;
        const float* row = &qlds[t * QPAD + gg * 16];
        float s = 0.0f;
#pragma unroll
        for (int k = 0; k < 16; ++k) s += row[k];
        out[t * NGRID + gbase + gg] = s * 0.0625f;
    }
}

extern "C" void kernel_launch(void* const* d_in, const int* in_sizes, int n_in,
                              void* d_out, int out_size, void* d_ws, size_t ws_size,
                              hipStream_t stream) {
    const float* x      = (const float*)d_in[0];
    const float* par    = (const float*)d_in[1];
    const int*   staind = (const int*)d_in[2];
    float*       out    = (float*)d_out;

    hipLaunchKernelGGL(hbv_kernel, dim3(NGRID / 4), dim3(64), 0, stream,
                       x, par, staind, out);
}